// Round 5
// baseline (23580.513 us; speedup 1.0000x reference)
//
#include <hip/hip_runtime.h>

#define NT 2048
#define NI 128
#define NH 256
#define WPG 32
#define BPG 8
#define ZROW 644  // [x(128)|h0(256)|h1(256)] + pad4 (bank-skew)

typedef unsigned long long u64;

__device__ __forceinline__ float sigm(float v) {
  return 1.0f / (1.0f + __expf(-v));
}
__device__ __forceinline__ float tanh_fast(float v) {
  v = fminf(fmaxf(v, -15.0f), 15.0f);
  float e = __expf(-2.0f * v);
  return (1.0f - e) / (1.0f + e);
}
__device__ __forceinline__ float lstm_act(float gi, float gf, float gg, float go,
                                          float& c) {
  const float ii = sigm(gi), ff = sigm(gf), gt = tanh_fast(gg), oo = sigm(go);
  c = ff * c + ii * gt;
  return oo * tanh_fast(c);
}

// relaxed agent-scope => coherent across XCDs, NO cache-maintenance ops.
__device__ __forceinline__ int ld_flag(const int* p) {
  return __hip_atomic_load(p, __ATOMIC_RELAXED, __HIP_MEMORY_SCOPE_AGENT);
}
__device__ __forceinline__ void st_flag(int* p, int v) {
  __hip_atomic_store(p, v, __ATOMIC_RELAXED, __HIP_MEMORY_SCOPE_AGENT);
}
__device__ __forceinline__ u64 ld_h64(const u64* p) {
  return __hip_atomic_load(p, __ATOMIC_RELAXED, __HIP_MEMORY_SCOPE_AGENT);
}
__device__ __forceinline__ void st_h64(u64* p, u64 v) {
  __hip_atomic_store(p, v, __ATOMIC_RELAXED, __HIP_MEMORY_SCOPE_AGENT);
}

template <int CTRL>
__device__ __forceinline__ float dppadd(float x) {
  int s = __builtin_amdgcn_update_dpp(0, __float_as_int(x), CTRL, 0xf, 0xf, true);
  return x + __int_as_float(s);
}
__device__ __forceinline__ float red16(float v) {
  v = dppadd<0xB1>(v);   // lane ^ 1
  v = dppadd<0x4E>(v);   // lane ^ 2
  v = dppadd<0x141>(v);  // lane ^ 7 (row_half_mirror)
  v = dppadd<0x140>(v);  // lane ^ 15 (row_mirror)
  return v;
}

// h layout: hX[parity][g][j][b_loc(8)][u(8)] -> each WG's publish = contiguous.
// Phase order per it: half A (batches 0-3), half B (4-7); layer-skewed
// (phase computes L0(it) and L1(it-1)). Poll+prefetch at phase START (load RT
// hides under the dot); publish = LDS gather -> wave1 single 32-lane u64 sc1
// store -> wave1-only vmcnt(0) -> flag (drain overlaps others' staging).
__global__ __launch_bounds__(512, 1) void lstm_persistent(
    const float* __restrict__ x,
    const float* __restrict__ wih0, const float* __restrict__ whh0,
    const float* __restrict__ bih0, const float* __restrict__ bhh0,
    const float* __restrict__ wih1, const float* __restrict__ whh1,
    const float* __restrict__ bih1, const float* __restrict__ bhh1,
    const float* __restrict__ fcw, const float* __restrict__ fcb,
    float* __restrict__ out,
    float* __restrict__ h0buf, float* __restrict__ h1buf,
    int* __restrict__ flags)
{
  extern __shared__ float sm[];
  float* zz  = sm;             // [4][ZROW]
  float* gat = sm + 4 * ZROW;  // [2][4][8] = [layer][b_loc][u]

  const int tid = threadIdx.x;
  const int bid = blockIdx.x;
  const int g = bid & 7;
  const int j = bid >> 3;
  const int b0 = g * BPG;
  int* fA = flags + g * WPG;
  int* fB = flags + 256 + g * WPG;

  const bool isL0 = (tid < 256);
  const int lane = tid & 63;
  const int wv = (tid & 255) >> 6;  // wave-in-layer 0..3
  const int ks = lane & 15;         // k-slice
  const int rg2 = (lane >> 4) & 1;  // unit-in-wave
  const int bg = lane >> 5;         // batch-pair
  const int u = wv * 2 + rg2;       // unit-local 0..7
  const int col = j * 8 + u;
  const int sel = ks & 1;           // lane's batch parity (act dedup)
  const int myb = bg * 2 + sel;     // lane's local batch 0..3

  // ---- weights + bias into registers (k = ks*4 + 64*c + e) ----
  float w[4][32];
  float bs[4];
  if (isL0) {
#pragma unroll
    for (int gt = 0; gt < 4; ++gt) {
      const int R = gt * NH + col;
      bs[gt] = bih0[R] + bhh0[R];
#pragma unroll
      for (int c = 0; c < 6; ++c)
#pragma unroll
        for (int e = 0; e < 4; ++e) {
          const int k = ks * 4 + 64 * c + e;
          w[gt][c * 4 + e] = (k < NI) ? wih0[R * NI + k] : whh0[R * NH + (k - NI)];
        }
    }
  } else {
#pragma unroll
    for (int gt = 0; gt < 4; ++gt) {
      const int R = gt * NH + col;
      bs[gt] = bih1[R] + bhh1[R];
#pragma unroll
      for (int c = 0; c < 8; ++c)
#pragma unroll
        for (int e = 0; e < 4; ++e) {
          const int k = ks * 4 + 64 * c + e;
          w[gt][c * 4 + e] = (k < NH) ? wih1[R * NH + k] : whh1[R * NH + (k - NH)];
        }
    }
  }

  // ---- hoisted per-thread constants ----
  const int pj = tid >> 4;  // j' 0..31 (prefetch/stage role)
  const int pr = tid & 15;
  const int pb = pr >> 2;   // local batch 0..3
  const int pu = pr & 3;    // u-pair 0..3
  const int stage_h0 = pb * ZROW + 128 + pj * 8 + pu * 2;
  const int stage_h1 = pb * ZROW + 384 + pj * 8 + pu * 2;
  const int pre_base = (g * 32 + pj) * 64 + pb * 8 + pu * 2;  // + oxb*8 + par*16384
  const float* xA = x + (size_t)(b0 + 0 + (tid >> 5)) * NT * NI + (tid & 31) * 4;
  const float* xB = x + (size_t)(b0 + 4 + (tid >> 5)) * NT * NI + (tid & 31) * 4;

  float cA = 0.f, cB = 0.f;  // cell for (u, myb) per half
  u64 rh0 = 0, rh1 = 0;
  float4 xv = make_float4(0.f, 0.f, 0.f, 0.f);
  if (tid < 128) xv = *reinterpret_cast<const float4*>(xA);  // A(0)
  __syncthreads();

#pragma unroll 1
  for (int it = 0; it <= NT; ++it) {
#pragma unroll
    for (int half = 0; half < 2; ++half) {
      const int xb = half ? 4 : 0;
      int* fSelf = half ? fB : fA;
      int* fOther = half ? fA : fB;
      const int nit = half ? it + 1 : it;  // prefetch-target iteration
      const int oxb = half ? 0 : 4;

      // ---- S1: stage regs -> LDS ----
      if (tid < 128 && it < NT)
        *reinterpret_cast<float4*>(&zz[(tid >> 5) * ZROW + (tid & 31) * 4]) = xv;
      *reinterpret_cast<u64*>(&zz[stage_h0]) = rh0;
      *reinterpret_cast<u64*>(&zz[stage_h1]) = rh1;
      __syncthreads();  // B1 (vm queues empty here by construction)

      // ---- S2: per-wave poll  +  S3: prefetch (hides under the dot) ----
      if (nit <= NT) {
        if (lane < WPG) {
          int guard = 0;
          while (ld_flag(&fOther[lane]) < nit) {
            __builtin_amdgcn_s_sleep(1);
            if (++guard > 50000000) break;
          }
        }
        asm volatile("" ::: "memory");  // keep prefetch below the poll
        const int o0 = ((nit - 1) & 1) * 16384 + oxb * 8 + pre_base;
        const int o1 = (nit & 1) * 16384 + oxb * 8 + pre_base;
        rh0 = ld_h64(reinterpret_cast<const u64*>(h0buf + o0));
        rh1 = ld_h64(reinterpret_cast<const u64*>(h1buf + o1));
        if (tid < 128 && nit < NT) {
          xv = *reinterpret_cast<const float4*>((half ? xA : xB) +
                                                (size_t)nit * NI);
        }
      }

      // ---- S4: dot + DPP reduce + act (once per lane) + LDS gather ----
      if (isL0 ? (it < NT) : (it >= 1)) {
        float acc[4][2] = {{0.f, 0.f}, {0.f, 0.f}, {0.f, 0.f}, {0.f, 0.f}};
        const int koff = isL0 ? (ks * 4) : (128 + ks * 4);
        const float* z0 = &zz[(bg * 2 + 0) * ZROW + koff];
        const float* z1 = &zz[(bg * 2 + 1) * ZROW + koff];
        const int NC = isL0 ? 6 : 8;
#pragma unroll
        for (int c = 0; c < 8; ++c) {
          if (c < NC) {
            const float4 v0 = *reinterpret_cast<const float4*>(z0 + 64 * c);
            const float4 v1 = *reinterpret_cast<const float4*>(z1 + 64 * c);
#pragma unroll
            for (int gt = 0; gt < 4; ++gt) {
              acc[gt][0] = fmaf(w[gt][c * 4 + 0], v0.x, acc[gt][0]);
              acc[gt][0] = fmaf(w[gt][c * 4 + 1], v0.y, acc[gt][0]);
              acc[gt][0] = fmaf(w[gt][c * 4 + 2], v0.z, acc[gt][0]);
              acc[gt][0] = fmaf(w[gt][c * 4 + 3], v0.w, acc[gt][0]);
              acc[gt][1] = fmaf(w[gt][c * 4 + 0], v1.x, acc[gt][1]);
              acc[gt][1] = fmaf(w[gt][c * 4 + 1], v1.y, acc[gt][1]);
              acc[gt][1] = fmaf(w[gt][c * 4 + 2], v1.z, acc[gt][1]);
              acc[gt][1] = fmaf(w[gt][c * 4 + 3], v1.w, acc[gt][1]);
            }
          }
        }
        float s0[4];
#pragma unroll
        for (int gt = 0; gt < 4; ++gt) {
          const float ra = red16(acc[gt][0]);
          const float rb = red16(acc[gt][1]);
          s0[gt] = (sel ? rb : ra) + bs[gt];
        }
        float c = half ? cB : cA;
        const float h = lstm_act(s0[0], s0[1], s0[2], s0[3], c);
        if (half) cB = c; else cA = c;
        if (ks < 2) gat[(isL0 ? 0 : 32) + myb * 8 + u] = h;
      }
      asm volatile("s_waitcnt lgkmcnt(0)" ::: "memory");
      __builtin_amdgcn_s_barrier();  // B2 (prefetches stay in flight)

      // ---- S5: wave1 publishes both layers (one 32-lane u64 sc1 store),
      //          drains its own acks, sets the flag ----
      if ((tid >> 6) == 1) {
        const int l = tid & 63;
        if (l < 32) {
          const int layer = l >> 4, l4 = l & 15;
          const bool ok = layer ? (it >= 1) : (it < NT);
          if (ok) {
            const int par = layer ? ((it - 1) & 1) : (it & 1);
            float* hb = layer ? h1buf : h0buf;
            const u64 v = *reinterpret_cast<const u64*>(
                &gat[layer * 32 + (l4 >> 2) * 8 + (l4 & 3) * 2]);
            st_h64(reinterpret_cast<u64*>(hb + par * 16384 + (g * 32 + j) * 64 +
                                          (xb + (l4 >> 2)) * 8 + (l4 & 3) * 2),
                   v);
          }
        }
        asm volatile("s_waitcnt vmcnt(0)" ::: "memory");
        if ((tid & 63) == 0) st_flag(&fSelf[j], it + 1);
      }
    }
  }

  // ---- epilogue: FC over relu(h1[T-1]) by WG j==0 of each group ----
  if (j == 0) {
    if (tid < WPG) {
      int guard = 0;
      while (ld_flag(&fA[tid]) < NT + 1 || ld_flag(&fB[tid]) < NT + 1) {
        __builtin_amdgcn_s_sleep(1);
        if (++guard > 50000000) break;
      }
    }
    __syncthreads();
    const int bb = tid >> 6, ln = tid & 63;  // 8 waves = 8 batches
    // h1 final: parity (NT-1)&1 = 1; element (j', bb, u)
    const int jj = ln >> 1, q = ln & 1;
    const float* src = h1buf + 1 * 16384 + ((8 * 0 + g) * 0) /*keep fmt*/ +
                       ((g * 32 + jj) * 8 + bb) * 8 + q * 4;
    const u64 u0 = ld_h64(reinterpret_cast<const u64*>(src));
    const u64 u1 = ld_h64(reinterpret_cast<const u64*>(src + 2));
    const float ha = __uint_as_float((unsigned)u0);
    const float hb = __uint_as_float((unsigned)(u0 >> 32));
    const float hc = __uint_as_float((unsigned)u1);
    const float hd = __uint_as_float((unsigned)(u1 >> 32));
    const float4 w4 = *reinterpret_cast<const float4*>(fcw + ln * 4);
    float p = fmaxf(ha, 0.f) * w4.x + fmaxf(hb, 0.f) * w4.y +
              fmaxf(hc, 0.f) * w4.z + fmaxf(hd, 0.f) * w4.w;
#pragma unroll
    for (int off = 32; off >= 1; off >>= 1) p += __shfl_down(p, off, 64);
    if (ln == 0) out[b0 + bb] = p + fcb[0];
  }
}

extern "C" void kernel_launch(void* const* d_in, const int* in_sizes, int n_in,
                              void* d_out, int out_size, void* d_ws, size_t ws_size,
                              hipStream_t stream) {
  (void)in_sizes; (void)n_in; (void)out_size; (void)ws_size;
  const float* x    = (const float*)d_in[0];
  const float* wih0 = (const float*)d_in[1];
  const float* whh0 = (const float*)d_in[2];
  const float* bih0 = (const float*)d_in[3];
  const float* bhh0 = (const float*)d_in[4];
  const float* wih1 = (const float*)d_in[5];
  const float* whh1 = (const float*)d_in[6];
  const float* bih1 = (const float*)d_in[7];
  const float* bhh1 = (const float*)d_in[8];
  const float* fcw  = (const float*)d_in[9];
  const float* fcb  = (const float*)d_in[10];
  float* out = (float*)d_out;

  float* ws = (float*)d_ws;
  float* h0buf = ws;                      // [2][8][32][8][8] f32 = 32768
  float* h1buf = ws + 32768;              // [2][8][32][8][8] f32
  int* flags = (int*)(ws + 65536);        // [2][8][32]

  const size_t zbytes = (size_t)65536 * sizeof(float) + 512 * sizeof(int);
  hipMemsetAsync(d_ws, 0, zbytes, stream);

  size_t shmem = 96 * 1024;  // force 1 WG/CU (co-residency, CU exclusivity)
  if (hipFuncSetAttribute(reinterpret_cast<const void*>(lstm_persistent),
                          hipFuncAttributeMaxDynamicSharedMemorySize,
                          (int)shmem) != hipSuccess) {
    shmem = (4 * ZROW + 64) * sizeof(float);  // real footprint fallback
  }

  hipLaunchKernelGGL(lstm_persistent, dim3(256), dim3(512), shmem, stream,
                     x, wih0, whh0, bih0, bhh0, wih1, whh1, bih1, bhh1,
                     fcw, fcb, out, h0buf, h1buf, flags);
}